// Round 7
// baseline (25280.775 us; speedup 1.0000x reference)
//
#include <hip/hip_runtime.h>
#include <cstdint>
#include <cstddef>

#define HS 512

constexpr int TPB  = 512;            // 8 waves/block
constexpr int GBLK = 64;
constexpr int OWNB = 24;             // owned carry rows per block (one per 16-lane group)

// ---------------- workspace layout (float offsets) ----------------
constexpr size_t OFF_TWrp  = 0;                       // [100][1536]
constexpr size_t OFF_TWwp  = OFF_TWrp  + 100*1536;    // [3][1536]
constexpr size_t OFF_TWwpa = OFF_TWwp  + 3*1536;      // [100][512]
constexpr size_t OFF_TWwpm = OFF_TWwpa + 100*512;
constexpr size_t OFF_TWca  = OFF_TWwpm + 100*512;     // [512][512]
constexpr size_t OFF_TWcm  = OFF_TWca  + 512*512;
constexpr size_t OFF_TWh0  = OFF_TWcm  + 512*512;     // W_rh[512:1024)^T   (h)
constexpr size_t OFF_TWh1  = OFF_TWh0  + 512*512;     // W_rha[2560:3072)^T (ha)
constexpr size_t OFF_TWh2  = OFF_TWh1  + 512*512;     // W_rhm[2560:3072)^T (hm)
constexpr size_t OFF_TWu0  = OFF_TWh2  + 512*512;     // W_rh[0:512)^T      (r)
constexpr size_t OFF_TWu1  = OFF_TWu0  + 512*512;     // W_rha[2048:2560)^T
constexpr size_t OFF_TWu2  = OFF_TWu1  + 512*512;     // W_rhm[2048:2560)^T
constexpr size_t OFF_PAca  = OFF_TWu2  + 512*512;     // [4096][512]
constexpr size_t OFF_PMcm  = OFF_PAca  + 4096*512;
constexpr size_t OFF_PArha = OFF_PMcm  + 4096*512;
constexpr size_t OFF_PMrhm = OFF_PArha + 4096*512;
constexpr size_t OFF_PAwpa = OFF_PMrhm + 4096*512;    // [4096][100]
constexpr size_t OFF_PMwpm = OFF_PAwpa + 4096*100;
constexpr size_t OFF_CARRY = OFF_PMwpm + 4096*100;    // u64[2][1536] tagged
constexpr size_t OFF_BCAST = OFF_CARRY + 2*1536*2;    // u64[2][1344] tagged
// bcast: [0:512) ca  [512:1024) cm  [1024:1124) grp  [1124:1224) gwpa
//        [1224:1324) gwpm  [1324:1327) wp

// ---------------- device helpers ----------------
__device__ __forceinline__ unsigned long long ald(const unsigned long long* p) {
  return __hip_atomic_load(const_cast<unsigned long long*>(p),
                           __ATOMIC_RELAXED, __HIP_MEMORY_SCOPE_AGENT);
}
__device__ __forceinline__ void gstTag(unsigned long long* p, float v, unsigned tag) {
  unsigned long long u = ((unsigned long long)tag << 32) | (unsigned long long)__float_as_uint(v);
  __hip_atomic_store(p, u, __ATOMIC_RELAXED, __HIP_MEMORY_SCOPE_AGENT);
}
__device__ __forceinline__ float xrsum(float v) {
  #pragma unroll
  for (int o = 32; o; o >>= 1) v += __shfl_xor(v, o, 64);
  return v;
}
__device__ __forceinline__ float rsum16(float v) {
  #pragma unroll
  for (int o = 8; o; o >>= 1) v += __shfl_xor(v, o, 64);
  return v;
}
// LDS flag spin: consumer side (compiler memory barrier after exit)
__device__ __forceinline__ void spinF(volatile unsigned* f, unsigned v) {
  while (*f < v) { }
  __builtin_amdgcn_sched_barrier(0);
  asm volatile("" ::: "memory");
}

// ---------------- prep kernels ----------------
__global__ void initK(unsigned long long* carryT, unsigned long long* bcast) {
  int i = blockIdx.x * blockDim.x + threadIdx.x, st = gridDim.x * blockDim.x;
  for (int k = i; k < 1536; k += st) carryT[k] = (1ull << 32);   // carry(0)=0, tag 1
  for (int k = i; k < 1536; k += st) carryT[1536 + k] = 0ull;
  for (int k = i; k < 2 * 1344; k += st) bcast[k] = 0ull;
}

__global__ void transK(const float* __restrict__ src, float* __restrict__ dst, int R, int C) {
  __shared__ float tile[32][33];
  int c0 = blockIdx.x * 32, r0 = blockIdx.y * 32;
  for (int i = threadIdx.y; i < 32; i += 8) {
    int r = r0 + i, c = c0 + threadIdx.x;
    tile[i][threadIdx.x] = (r < R && c < C) ? src[(size_t)r * C + c] : 0.f;
  }
  __syncthreads();
  for (int i = threadIdx.y; i < 32; i += 8) {
    int c = c0 + i, r = r0 + threadIdx.x;
    if (c < C && r < R) dst[(size_t)c * R + r] = tile[threadIdx.x][i];
  }
}

__global__ __launch_bounds__(256) void gemmK(const float* __restrict__ X,
                                             const float* __restrict__ W,
                                             float* __restrict__ C, int N) {
  __shared__ float As[16][68];
  __shared__ float Bs[16][68];
  int t0 = blockIdx.y * 64, n0 = blockIdx.x * 64;
  int tid = threadIdx.x, tx = tid & 15, ty = tid >> 4;
  float acc[4][4] = {};
  for (int k0 = 0; k0 < 2048; k0 += 16) {
    {
      int r = tid >> 2, c = (tid & 3) * 4;
      float4 v = *(const float4*)(X + (size_t)(t0 + r) * 2048 + k0 + c);
      As[c + 0][r] = v.x; As[c + 1][r] = v.y; As[c + 2][r] = v.z; As[c + 3][r] = v.w;
    }
    {
      int kr = tid >> 4, c = (tid & 15) * 4;
      int gcol = n0 + c;
      const float* src = W + (size_t)(k0 + kr) * N + gcol;
      #pragma unroll
      for (int i = 0; i < 4; ++i) Bs[kr][c + i] = (gcol + i < N) ? src[i] : 0.f;
    }
    __syncthreads();
    #pragma unroll
    for (int kk = 0; kk < 16; ++kk) {
      float4 a4 = *(const float4*)&As[kk][ty * 4];
      float4 b4 = *(const float4*)&Bs[kk][tx * 4];
      float av[4] = {a4.x, a4.y, a4.z, a4.w};
      float bv[4] = {b4.x, b4.y, b4.z, b4.w};
      #pragma unroll
      for (int i = 0; i < 4; ++i)
        #pragma unroll
        for (int j = 0; j < 4; ++j) acc[i][j] += av[i] * bv[j];
    }
    __syncthreads();
  }
  #pragma unroll
  for (int i = 0; i < 4; ++i)
    #pragma unroll
    for (int j = 0; j < 4; ++j) {
      int col = n0 + tx * 4 + j;
      if (col < N) C[(size_t)(t0 + ty * 4 + i) * N + col] = acc[i][j];
    }
}

__global__ __launch_bounds__(256) void gemm128(const float* __restrict__ X,
                                               const float* __restrict__ W,
                                               float* __restrict__ C) {
  __shared__ float As[8][132];
  __shared__ float Bs[8][132];
  const int N = 512;
  int t0 = blockIdx.y * 128, n0 = blockIdx.x * 128;
  int tid = threadIdx.x, tx = tid & 15, ty = tid >> 4;
  float acc[8][8] = {};
  for (int k0 = 0; k0 < 2048; k0 += 8) {
    int r = tid >> 1, c4 = (tid & 1) * 4;
    float4 va = *(const float4*)(X + (size_t)(t0 + r) * 2048 + k0 + c4);
    int kr = tid >> 5, cb = (tid & 31) * 4;
    float4 vb = *(const float4*)(W + (size_t)(k0 + kr) * N + n0 + cb);
    __syncthreads();
    As[c4 + 0][r] = va.x; As[c4 + 1][r] = va.y; As[c4 + 2][r] = va.z; As[c4 + 3][r] = va.w;
    Bs[kr][cb] = vb.x; Bs[kr][cb + 1] = vb.y; Bs[kr][cb + 2] = vb.z; Bs[kr][cb + 3] = vb.w;
    __syncthreads();
    #pragma unroll
    for (int kk = 0; kk < 8; ++kk) {
      float av[8], bv[8];
      *(float4*)av       = *(const float4*)&As[kk][ty * 8];
      *(float4*)(av + 4) = *(const float4*)&As[kk][ty * 8 + 4];
      *(float4*)bv       = *(const float4*)&Bs[kk][tx * 8];
      *(float4*)(bv + 4) = *(const float4*)&Bs[kk][tx * 8 + 4];
      #pragma unroll
      for (int i = 0; i < 8; ++i)
        #pragma unroll
        for (int j = 0; j < 8; ++j) acc[i][j] += av[i] * bv[j];
    }
  }
  #pragma unroll
  for (int i = 0; i < 8; ++i) {
    float* dst = C + (size_t)(t0 + ty * 8 + i) * N + n0 + tx * 8;
    *(float4*)dst       = *(float4*)&acc[i][0];
    *(float4*)(dst + 4) = *(float4*)&acc[i][4];
  }
}

// ---------------- persistent recurrence kernel ----------------
struct RArgs {
  const float *TWrp, *TWwp, *TWwpa, *TWwpm, *TWca, *TWcm;
  const float *TWh0, *TWh1, *TWh2, *TWu0, *TWu1, *TWu2;
  const float *PAca, *PMcm, *PArha, *PMrhm, *PAwpa, *PMwpm;
  const float *b_ca, *b_cm, *b_wp, *b_wpa, *b_wpm, *b_rp, *b_rh, *b_rha, *b_rhm;
  unsigned long long *carryT, *bcast;
  float *out;
  int nT;
};

__global__ __launch_bounds__(TPB, 1) void recurK(RArgs a) {
  const int tid  = threadIdx.x;
  const int lane = tid & 63;
  const int lw   = tid >> 6;                 // wave 0..7
  const int g    = tid >> 4;                 // 16-lane group 0..31
  const int gl   = tid & 15;
  const int b    = blockIdx.x;

  // ---- LDS (~12 KB) ----
  __shared__ __align__(16) float s_x[1536];          // carry [ha|hm|h]
  __shared__ __align__(16) float s_c[1024];          // [ca|cm]
  __shared__ float s_ar[112], s_awa[112], s_awm[112], s_aw[4];
  __shared__ unsigned s_flags[8];   // 0 fAr, 1 fAw, 2 fAwa, 3 fAwm, 4 fC6, 5 fC7
  volatile unsigned* FL = s_flags;

  // ---- static assignment maps ----
  const int r0a = (b + 51) & 63;                 // gwpa rows r0a, r0a+64(if<36)
  const int r1m = (b + 25) & 63;                 // gwpm rows
  const bool big1_grp = (b < 36);
  const bool big1_wp  = (b >= 40 && b <= 42);

  if (tid < 112) { s_ar[tid] = 0.f; s_awa[tid] = 0.f; s_awm[tid] = 0.f; }
  if (tid < 8) s_flags[tid] = 0u;

  // ---- per-thread roles ----
  int dstA = -1, xoffA = 0, strideA = 512;
  bool reluA = false;
  float biasA = 0.f;
  const float* preAPtr = nullptr;
  const float* wARow = nullptr;
  if (lw < 2) {
    int col = b * 8 + g;
    dstA = col; reluA = true; biasA = a.b_ca[col]; preAPtr = a.PAca + col;
    wARow = a.TWca + (size_t)col * 512; xoffA = 0;
  } else if (lw < 4) {
    int col = b * 8 + (g - 8);
    dstA = 512 + col; reluA = true; biasA = a.b_cm[col]; preAPtr = a.PMcm + col;
    wARow = a.TWcm + (size_t)col * 512; xoffA = 512;
  } else if (lw == 4) {
    int sl = g - 16;
    strideA = 100;
    if (sl == 0)                  { dstA = 1124 + r0a;      biasA = a.b_wpa[r0a];      preAPtr = a.PAwpa + r0a;      wARow = a.TWwpa + (size_t)r0a * 512;        xoffA = 0;   }
    else if (sl == 1 && r0a < 36) { dstA = 1124 + r0a + 64; biasA = a.b_wpa[r0a + 64]; preAPtr = a.PAwpa + r0a + 64; wARow = a.TWwpa + (size_t)(r0a + 64) * 512; xoffA = 0;   }
    else if (sl == 2)             { dstA = 1224 + r1m;      biasA = a.b_wpm[r1m];      preAPtr = a.PMwpm + r1m;      wARow = a.TWwpm + (size_t)r1m * 512;        xoffA = 512; }
    else if (sl == 3 && r1m < 36) { dstA = 1224 + r1m + 64; biasA = a.b_wpm[r1m + 64]; preAPtr = a.PMwpm + r1m + 64; wARow = a.TWwpm + (size_t)(r1m + 64) * 512; xoffA = 512; }
  }
  int dstBig = -1;
  float biasBig = 0.f;
  const float* wBigRow = nullptr;
  if (lw == 6) { dstBig = 1024 + b; biasBig = a.b_rp[b]; wBigRow = a.TWrp + (size_t)b * 1536; }
  else if (lw == 7) {
    if (big1_grp)      { dstBig = 1024 + b + 64;   biasBig = a.b_rp[b + 64]; wBigRow = a.TWrp + (size_t)(b + 64) * 1536; }
    else if (big1_wp)  { dstBig = 1324 + (b - 40); biasBig = a.b_wp[b - 40]; wBigRow = a.TWwp + (size_t)(b - 40) * 1536; }
  }
  const bool own = (g < OWNB);
  int ownHsel = 0, ownJ = 0, whXo = 0;
  float biasO = 0.f;
  const float* preOPtr = nullptr;
  const float* whRow = nullptr;
  const float* uRow = nullptr;
  if (own) {
    int q = b * OWNB + g, hsel = q >> 9, j = q & 511;
    ownHsel = hsel; ownJ = j;
    if (hsel == 0)      { biasO = a.b_rh[j];
                          whRow = a.TWh0 + (size_t)j * 512; whXo = 1024;
                          uRow  = a.TWu0 + (size_t)j * 512; }
    else if (hsel == 1) { biasO = a.b_rha[j]; preOPtr = a.PArha + j;
                          whRow = a.TWh1 + (size_t)j * 512; whXo = 0;
                          uRow  = a.TWu1 + (size_t)j * 512; }
    else                { biasO = a.b_rhm[j]; preOPtr = a.PMrhm + j;
                          whRow = a.TWh2 + (size_t)j * 512; whXo = 512;
                          uRow  = a.TWu2 + (size_t)j * 512; }
  }

  // ---- register-pinned weights (time-invariant; loaded once) ----
  float4 wA[8];   // phase-A row slice
  float4 wU[8];   // owned u-row slice
  float4 wWh[8];  // owned wh-row slice
  float4 wB[6];   // big-gate row slice
  float  gr[7];   // G memory rows (private to owning group)
  #pragma unroll
  for (int it = 0; it < 8; ++it) wA[it] = wU[it] = wWh[it] = make_float4(0.f, 0.f, 0.f, 0.f);
  #pragma unroll
  for (int it = 0; it < 6; ++it) wB[it] = make_float4(0.f, 0.f, 0.f, 0.f);
  #pragma unroll
  for (int k = 0; k < 7; ++k) gr[k] = 0.f;

  if (wARow) {
    const float4* w4 = (const float4*)wARow;
    #pragma unroll
    for (int it = 0; it < 8; ++it) wA[it] = w4[gl + 16 * it];
  }
  if (own) {
    const float4* u4 = (const float4*)uRow;
    const float4* h4 = (const float4*)whRow;
    #pragma unroll
    for (int it = 0; it < 8; ++it) { wU[it] = u4[gl + 16 * it]; wWh[it] = h4[gl + 16 * it]; }
  }
  if (wBigRow) {
    const float4* w4 = (const float4*)wBigRow;
    #pragma unroll
    for (int it = 0; it < 6; ++it) wB[it] = w4[lane + 64 * it];
  }
  __syncthreads();

  // ---- prologue: software-pipelined per-step scalars (value for t=0) ----
  float preA_c = preAPtr ? preAPtr[0] : 0.f;
  float preO_c = preOPtr ? preOPtr[0] : 0.f;

  // ---------------- time loop (single barrier per step) ----------------
  float whv = 0.f;
  for (int t = 0; t < a.nT; ++t) {
    const unsigned tagB = (unsigned)t + 1;
    unsigned long long* bc = a.bcast + (size_t)(t & 1) * 1344;

    // ---- poll carry(t): 3 slots/thread ----
    {
      const unsigned long long* cin = a.carryT + (size_t)(t & 1) * 1536;
      int i0 = tid, i1 = tid + 512, i2 = tid + 1024;
      unsigned long long v0 = ald(cin + i0), v1 = ald(cin + i1), v2 = ald(cin + i2);
      while (((unsigned)(v0 >> 32) < tagB) | ((unsigned)(v1 >> 32) < tagB) |
             ((unsigned)(v2 >> 32) < tagB)) {
        __builtin_amdgcn_s_sleep(1);
        v0 = ald(cin + i0); v1 = ald(cin + i1); v2 = ald(cin + i2);
      }
      s_x[i0] = __uint_as_float((unsigned)v0);
      s_x[i1] = __uint_as_float((unsigned)v1);
      s_x[i2] = __uint_as_float((unsigned)v2);
    }
    __syncthreads();   // SYNC0 — the ONLY barrier per step; fences all step t-1 work

    // issue NEXT step's prefetches now (whole step to land)
    const int tn = (t + 1 < a.nT) ? t + 1 : t;
    float preA_n = preAPtr ? preAPtr[(size_t)tn * strideA] : 0.f;
    float preO_n = preOPtr ? preOPtr[(size_t)tn * 512] : 0.f;

    // ---- phase A: all publishes in one parallel round ----
    if (dstA >= 0) {
      const float4* x4 = (const float4*)(s_x + xoffA);
      float acc = 0.f;
      #pragma unroll
      for (int it = 0; it < 8; ++it) {
        float4 xv = x4[gl + 16 * it];
        acc += wA[it].x * xv.x + wA[it].y * xv.y + wA[it].z * xv.z + wA[it].w * xv.w;
      }
      float v = rsum16(acc);
      if (!gl) {
        v += preA_c + biasA;
        if (reluA) v = fmaxf(v, 0.f);
        gstTag(bc + dstA, v, tagB);
      }
    } else if (dstBig >= 0) {
      const float4* x4 = (const float4*)s_x;
      float acc = 0.f;
      #pragma unroll
      for (int it = 0; it < 6; ++it) {
        float4 xv = x4[lane + 64 * it];
        acc += wB[it].x * xv.x + wB[it].y * xv.y + wB[it].z * xv.z + wB[it].w * xv.w;
      }
      float v = xrsum(acc);
      if (!lane) gstTag(bc + dstBig, v + biasBig, tagB);
    }
    // wh dot (register weights; needed for h')
    if (own) {
      const float4* x4 = (const float4*)(s_x + whXo);
      float acc = 0.f;
      #pragma unroll
      for (int it = 0; it < 8; ++it) {
        float4 xv = x4[gl + 16 * it];
        acc += wWh[it].x * xv.x + wWh[it].y * xv.y + wWh[it].z * xv.z + wWh[it].w * xv.w;
      }
      whv = rsum16(acc);
    }

    // ---- CRITICAL: wave 0 produces ar (softmax over grp logits) ----
    if (lw == 0) {
      const unsigned long long* p1 = bc + 1024 + lane;
      bool two = lane < 36;
      bool wpx = (lane >= 40 && lane < 43);
      const unsigned long long* pw = bc + 1324 + (lane - 40);
      unsigned long long v1 = ald(p1);
      unsigned long long v2 = two ? ald(p1 + 64) : ~0ull;
      unsigned long long vw = wpx ? ald(pw) : ~0ull;
      while (((unsigned)(v1 >> 32) < tagB) | ((unsigned)(v2 >> 32) < tagB) |
             ((unsigned)(vw >> 32) < tagB)) {
        __builtin_amdgcn_s_sleep(1);
        v1 = ald(p1); if (two) v2 = ald(p1 + 64); if (wpx) vw = ald(pw);
      }
      // (vw only tag-checked: fences wp-blocks' wave-7 s_x reads before fAr)
      float x1 = __uint_as_float((unsigned)v1);
      float x2 = two ? __uint_as_float((unsigned)v2) : -3.0e38f;
      float m = fmaxf(x1, x2);
      #pragma unroll
      for (int o = 32; o; o >>= 1) m = fmaxf(m, __shfl_xor(m, o, 64));
      float e1 = expf(x1 - m);
      float e2 = two ? expf(x2 - m) : 0.f;
      float ss = e1 + e2;
      #pragma unroll
      for (int o = 32; o; o >>= 1) ss += __shfl_xor(ss, o, 64);
      float inv = 1.f / ss;
      s_ar[lane] = e1 * inv;
      if (two) s_ar[64 + lane] = e2 * inv;
      asm volatile("s_waitcnt lgkmcnt(0)" ::: "memory");
      if (!lane) FL[0] = tagB;   // fAr
    }

    // ---- CRITICAL: owners publish h' as soon as ar is ready ----
    unsigned long long* cout = a.carryT + (size_t)((t + 1) & 1) * 1536;
    if (own) {
      spinF(&FL[0], tagB);
      float contrib = 0.f;
      #pragma unroll
      for (int k = 0; k < 7; ++k) contrib += s_ar[gl + 16 * k] * gr[k];
      contrib = rsum16(contrib);
      if (!gl) {
        float h = fmaxf(contrib + whv + preO_c + biasO, 0.f);
        if (ownHsel == 0) {
          a.out[(size_t)t * 512 + ownJ] = h;
          gstTag(cout + 1024 + ownJ, h, tagB + 1);
        } else if (ownHsel == 1) {
          gstTag(cout + ownJ, h, tagB + 1);
        } else {
          gstTag(cout + 512 + ownJ, h, tagB + 1);
        }
      }
    }

    // ---- off-critical role work (after the h' publish) ----
    if (lw == 1) {            // awa softmax
      const unsigned long long* p1 = bc + 1124 + lane;
      bool two = lane < 36;
      unsigned long long v1 = ald(p1);
      unsigned long long v2 = two ? ald(p1 + 64) : ~0ull;
      while (((unsigned)(v1 >> 32) < tagB) | ((unsigned)(v2 >> 32) < tagB)) {
        __builtin_amdgcn_s_sleep(1);
        v1 = ald(p1); if (two) v2 = ald(p1 + 64);
      }
      float x1 = __uint_as_float((unsigned)v1);
      float x2 = two ? __uint_as_float((unsigned)v2) : -3.0e38f;
      float m = fmaxf(x1, x2);
      #pragma unroll
      for (int o = 32; o; o >>= 1) m = fmaxf(m, __shfl_xor(m, o, 64));
      float e1 = expf(x1 - m);
      float e2 = two ? expf(x2 - m) : 0.f;
      float ss = e1 + e2;
      #pragma unroll
      for (int o = 32; o; o >>= 1) ss += __shfl_xor(ss, o, 64);
      float inv = 1.f / ss;
      s_awa[lane] = e1 * inv;
      if (two) s_awa[64 + lane] = e2 * inv;
      asm volatile("s_waitcnt lgkmcnt(0)" ::: "memory");
      if (!lane) FL[2] = tagB;  // fAwa
    } else if (lw == 2) {     // awm softmax
      const unsigned long long* p1 = bc + 1224 + lane;
      bool two = lane < 36;
      unsigned long long v1 = ald(p1);
      unsigned long long v2 = two ? ald(p1 + 64) : ~0ull;
      while (((unsigned)(v1 >> 32) < tagB) | ((unsigned)(v2 >> 32) < tagB)) {
        __builtin_amdgcn_s_sleep(1);
        v1 = ald(p1); if (two) v2 = ald(p1 + 64);
      }
      float x1 = __uint_as_float((unsigned)v1);
      float x2 = two ? __uint_as_float((unsigned)v2) : -3.0e38f;
      float m = fmaxf(x1, x2);
      #pragma unroll
      for (int o = 32; o; o >>= 1) m = fmaxf(m, __shfl_xor(m, o, 64));
      float e1 = expf(x1 - m);
      float e2 = two ? expf(x2 - m) : 0.f;
      float ss = e1 + e2;
      #pragma unroll
      for (int o = 32; o; o >>= 1) ss += __shfl_xor(ss, o, 64);
      float inv = 1.f / ss;
      s_awm[lane] = e1 * inv;
      if (two) s_awm[64 + lane] = e2 * inv;
      asm volatile("s_waitcnt lgkmcnt(0)" ::: "memory");
      if (!lane) FL[3] = tagB;  // fAwm
    } else if (lw == 3) {     // wp softmax
      float x = -3.0e38f;
      if (lane < 3) {
        const unsigned long long* p = bc + 1324 + lane;
        unsigned long long v = ald(p);
        while ((unsigned)(v >> 32) < tagB) { __builtin_amdgcn_s_sleep(1); v = ald(p); }
        x = __uint_as_float((unsigned)v);
      }
      float m = x;
      #pragma unroll
      for (int o = 32; o; o >>= 1) m = fmaxf(m, __shfl_xor(m, o, 64));
      float e = (lane < 3) ? expf(x - m) : 0.f;
      float ss = e;
      #pragma unroll
      for (int o = 32; o; o >>= 1) ss += __shfl_xor(ss, o, 64);
      if (lane < 3) s_aw[lane] = e / ss;
      asm volatile("s_waitcnt lgkmcnt(0)" ::: "memory");
      if (!lane) FL[1] = tagB;  // fAw
    } else if (lw >= 6) {     // c-gather on waves 6/7 (idle after big publish)
      int ci = tid - 384;     // 0..127, 8 slots each (stride 128)
      const unsigned long long* p = bc + ci;
      unsigned long long v[8];
      #pragma unroll
      for (int k = 0; k < 8; ++k) v[k] = ald(p + 128 * k);
      for (;;) {
        bool ok = true;
        #pragma unroll
        for (int k = 0; k < 8; ++k) ok &= ((unsigned)(v[k] >> 32) >= tagB);
        if (__all(ok)) break;
        __builtin_amdgcn_s_sleep(1);
        #pragma unroll
        for (int k = 0; k < 8; ++k) v[k] = ald(p + 128 * k);
      }
      #pragma unroll
      for (int k = 0; k < 8; ++k) s_c[ci + 128 * k] = __uint_as_float((unsigned)v[k]);
      asm volatile("s_waitcnt lgkmcnt(0)" ::: "memory");
      if (!lane) FL[4 + (lw - 6)] = tagB;  // fC6 / fC7
    }

    // ---- owners' off-critical tail: u-dot + G update ----
    if (own) {
      spinF(&FL[4], tagB);
      spinF(&FL[5], tagB);
      const float4* a4 = (const float4*)s_c;
      const float4* m4 = (const float4*)(s_c + 512);
      float sa = 0.f, sm = 0.f;
      #pragma unroll
      for (int it = 0; it < 8; ++it) {
        float4 av = a4[gl + 16 * it], mv = m4[gl + 16 * it];
        sa += wU[it].x * av.x + wU[it].y * av.y + wU[it].z * av.z + wU[it].w * av.w;
        sm += wU[it].x * mv.x + wU[it].y * mv.y + wU[it].z * mv.z + wU[it].w * mv.w;
      }
      #pragma unroll
      for (int o = 8; o; o >>= 1) { sa += __shfl_xor(sa, o, 64); sm += __shfl_xor(sm, o, 64); }
      const float uA = sa, uM = sm;

      spinF(&FL[1], tagB);
      spinF(&FL[2], tagB);
      spinF(&FL[3], tagB);
      const float aw0 = s_aw[0], aw1 = s_aw[1], aw2 = s_aw[2];
      #pragma unroll
      for (int k = 0; k < 7; ++k) {
        int idx = gl + 16 * k;
        gr[k] = aw0 * gr[k] + aw1 * s_awa[idx] * uA + aw2 * s_awm[idx] * uM;
      }
    }

    // rotate the pipelined prefetch registers
    preA_c = preA_n;
    preO_c = preO_n;
  }
}

// ---------------- host ----------------
extern "C" void kernel_launch(void* const* d_in, const int* in_sizes, int n_in,
                              void* d_out, int out_size, void* d_ws, size_t ws_size,
                              hipStream_t stream) {
  const float* Xa    = (const float*)d_in[0];
  const float* Xm    = (const float*)d_in[1];
  const float* W_ca  = (const float*)d_in[2];  const float* b_ca  = (const float*)d_in[3];
  const float* W_cm  = (const float*)d_in[4];  const float* b_cm  = (const float*)d_in[5];
  const float* W_wp  = (const float*)d_in[6];  const float* b_wp  = (const float*)d_in[7];
  const float* W_wpa = (const float*)d_in[8];  const float* b_wpa = (const float*)d_in[9];
  const float* W_wpm = (const float*)d_in[10]; const float* b_wpm = (const float*)d_in[11];
  const float* W_rp  = (const float*)d_in[12]; const float* b_rp  = (const float*)d_in[13];
  const float* W_rh  = (const float*)d_in[14]; const float* b_rh  = (const float*)d_in[15];
  const float* W_rha = (const float*)d_in[16]; const float* b_rha = (const float*)d_in[17];
  const float* W_rhm = (const float*)d_in[18]; const float* b_rhm = (const float*)d_in[19];

  int nT = out_size / HS;   // 4096
  float* ws = (float*)d_ws;

  initK<<<dim3(64), dim3(256), 0, stream>>>(
      (unsigned long long*)(ws + OFF_CARRY),
      (unsigned long long*)(ws + OFF_BCAST));

  dim3 tb(32, 8);
  auto tg = [](int R, int C) { return dim3((C + 31) / 32, (R + 31) / 32); };
  transK<<<tg(1536, 100), tb, 0, stream>>>(W_rp,                       ws + OFF_TWrp,  1536, 100);
  transK<<<tg(1536, 3),   tb, 0, stream>>>(W_wp,                       ws + OFF_TWwp,  1536, 3);
  transK<<<tg(512, 100),  tb, 0, stream>>>(W_wpa,                      ws + OFF_TWwpa, 512, 100);
  transK<<<tg(512, 100),  tb, 0, stream>>>(W_wpm,                      ws + OFF_TWwpm, 512, 100);
  transK<<<tg(512, 512),  tb, 0, stream>>>(W_ca,                       ws + OFF_TWca,  512, 512);
  transK<<<tg(512, 512),  tb, 0, stream>>>(W_cm,                       ws + OFF_TWcm,  512, 512);
  transK<<<tg(512, 512),  tb, 0, stream>>>(W_rh  + 512 * 512,          ws + OFF_TWh0,  512, 512);
  transK<<<tg(512, 512),  tb, 0, stream>>>(W_rha + (size_t)2560 * 512, ws + OFF_TWh1,  512, 512);
  transK<<<tg(512, 512),  tb, 0, stream>>>(W_rhm + (size_t)2560 * 512, ws + OFF_TWh2,  512, 512);
  transK<<<tg(512, 512),  tb, 0, stream>>>(W_rh,                       ws + OFF_TWu0,  512, 512);
  transK<<<tg(512, 512),  tb, 0, stream>>>(W_rha + (size_t)2048 * 512, ws + OFF_TWu1,  512, 512);
  transK<<<tg(512, 512),  tb, 0, stream>>>(W_rhm + (size_t)2048 * 512, ws + OFF_TWu2,  512, 512);

  int tB = nT / 128;
  gemm128<<<dim3(4, tB), dim3(256), 0, stream>>>(Xa, W_ca + (size_t)512 * 512, ws + OFF_PAca);
  gemm128<<<dim3(4, tB), dim3(256), 0, stream>>>(Xm, W_cm + (size_t)512 * 512, ws + OFF_PMcm);
  gemm128<<<dim3(4, tB), dim3(256), 0, stream>>>(Xa, W_rha,                    ws + OFF_PArha);
  gemm128<<<dim3(4, tB), dim3(256), 0, stream>>>(Xm, W_rhm,                    ws + OFF_PMrhm);
  int tB64 = nT / 64;
  gemmK<<<dim3(2, tB64), dim3(256), 0, stream>>>(Xa, W_wpa + (size_t)512 * 100, ws + OFF_PAwpa, 100);
  gemmK<<<dim3(2, tB64), dim3(256), 0, stream>>>(Xm, W_wpm + (size_t)512 * 100, ws + OFF_PMwpm, 100);

  RArgs a;
  a.TWrp  = ws + OFF_TWrp;  a.TWwp  = ws + OFF_TWwp;
  a.TWwpa = ws + OFF_TWwpa; a.TWwpm = ws + OFF_TWwpm;
  a.TWca  = ws + OFF_TWca;  a.TWcm  = ws + OFF_TWcm;
  a.TWh0  = ws + OFF_TWh0;  a.TWh1  = ws + OFF_TWh1;  a.TWh2 = ws + OFF_TWh2;
  a.TWu0  = ws + OFF_TWu0;  a.TWu1  = ws + OFF_TWu1;  a.TWu2 = ws + OFF_TWu2;
  a.PAca  = ws + OFF_PAca;  a.PMcm  = ws + OFF_PMcm;
  a.PArha = ws + OFF_PArha; a.PMrhm = ws + OFF_PMrhm;
  a.PAwpa = ws + OFF_PAwpa; a.PMwpm = ws + OFF_PMwpm;
  a.b_ca = b_ca; a.b_cm = b_cm; a.b_wp = b_wp; a.b_wpa = b_wpa; a.b_wpm = b_wpm;
  a.b_rp = b_rp; a.b_rh = b_rh; a.b_rha = b_rha; a.b_rhm = b_rhm;
  a.carryT = (unsigned long long*)(ws + OFF_CARRY);
  a.bcast  = (unsigned long long*)(ws + OFF_BCAST);
  a.out    = (float*)d_out;
  a.nT     = nT;

  recurK<<<dim3(GBLK), dim3(TPB), 0, stream>>>(a);
}